// Round 2
// baseline (67.135 us; speedup 1.0000x reference)
//
#include <hip/hip_runtime.h>

// CTRMultiEmbedding: joint embedding gather + bilinear interval embedding.
// out = [joint (B,L,D) | delta (B,L,L,D)] concatenated, float32.
// delta[b,i,j,d] = base[m][d] + ds*cs[m][d] + dt*ct[m][d]
//   m = (i<len_b && j<len_b); base = e_sl+e_tl, cs = e_su-e_sl, ct = e_tu-e_tl.
//
// Grid is exactly 2^19 threads; stride == 2^19, so per-thread d-offset and
// (i,j) are loop-invariant and the loop index IS the batch index. All
// coefficients live in registers; loop is fully unrolled over b=0..7.

typedef float f4 __attribute__((ext_vector_type(4)));
typedef float f2 __attribute__((ext_vector_type(2)));

constexpr int HOURS   = 168;
constexpr int Dd      = 64;
constexpr int NJOINT  = 8 * 256 * 64;      // 131072 floats
constexpr int DELTA_IT_STRIDE = 524288 * 8; // floats advanced per iteration

__device__ __forceinline__ f4 ld4(const float* p) {
    return *reinterpret_cast<const f4*>(p);
}
__device__ __forceinline__ void st4nt(float* p, f4 v) {
    __builtin_nontemporal_store(v, reinterpret_cast<f4*>(p));
}

__global__ __launch_bounds__(256) void ctr_fused_kernel(
    const int*   __restrict__ traj,     // (B,L,3) int32
    const float* __restrict__ mat,      // (B,L,L,2)
    const int*   __restrict__ lens,     // (B)
    const float* __restrict__ emb_t,    // (169,64)
    const float* __restrict__ emb_l,    // (50000,64)
    const float* __restrict__ emb_u,    // (10000,64)
    const float* __restrict__ emb_su,   // (2,64)
    const float* __restrict__ emb_sl,
    const float* __restrict__ emb_tu,
    const float* __restrict__ emb_tl,
    float* __restrict__ out)
{
    const int tid_g = blockIdx.x * 256 + threadIdx.x;   // 0 .. 2^19-1
    const int dof   = (tid_g & 7) * 8;                  // float offset in D, invariant

    // ---- joint embedding: first 16384 threads, 32B each ----
    if (tid_g < NJOINT / 8) {
        int row  = tid_g >> 3;
        int user = traj[row * 3 + 0];
        int loc  = traj[row * 3 + 1];
        int t    = traj[row * 3 + 2];
        int tm   = (t - 1) % HOURS;                     // python modulo fixup
        if (tm < 0) tm += HOURS;
        int tx = tm + 1;
        f4 a0 = ld4(emb_t + tx * Dd + dof),  a1 = ld4(emb_t + tx * Dd + dof + 4);
        f4 l0 = ld4(emb_l + loc * Dd + dof), l1 = ld4(emb_l + loc * Dd + dof + 4);
        f4 u0 = ld4(emb_u + user * Dd + dof), u1 = ld4(emb_u + user * Dd + dof + 4);
        st4nt(out + row * Dd + dof,     a0 + l0 + u0);
        st4nt(out + row * Dd + dof + 4, a1 + l1 + u1);
    }

    // ---- hoist interpolation coefficients into registers (12 x f4) ----
    f4 sl0a = ld4(emb_sl + dof),      sl0b = ld4(emb_sl + dof + 4);
    f4 sl1a = ld4(emb_sl + 64 + dof), sl1b = ld4(emb_sl + 64 + dof + 4);
    f4 su0a = ld4(emb_su + dof),      su0b = ld4(emb_su + dof + 4);
    f4 su1a = ld4(emb_su + 64 + dof), su1b = ld4(emb_su + 64 + dof + 4);
    f4 tl0a = ld4(emb_tl + dof),      tl0b = ld4(emb_tl + dof + 4);
    f4 tl1a = ld4(emb_tl + 64 + dof), tl1b = ld4(emb_tl + 64 + dof + 4);
    f4 tu0a = ld4(emb_tu + dof),      tu0b = ld4(emb_tu + dof + 4);
    f4 tu1a = ld4(emb_tu + 64 + dof), tu1b = ld4(emb_tu + 64 + dof + 4);

    f4 base0a = sl0a + tl0a, base0b = sl0b + tl0b;
    f4 base1a = sl1a + tl1a, base1b = sl1b + tl1b;
    f4 cs0a = su0a - sl0a,   cs0b = su0b - sl0b;
    f4 cs1a = su1a - sl1a,   cs1b = su1b - sl1b;
    f4 ct0a = tu0a - tl0a,   ct0b = tu0b - tl0b;
    f4 ct1a = tu1a - tl1a,   ct1b = tu1b - tl1b;

    // ---- delta embedding: 8 iterations, iteration index == batch index ----
    const int p0 = tid_g >> 3;       // pair index within batch 0: i*256 + j
    const int j  = p0 & 255;
    const int i  = p0 >> 8;
    const float* matp = mat + (size_t)p0 * 2;
    float*       outp = out + NJOINT + (size_t)tid_g * 8;

#pragma unroll
    for (int it = 0; it < 8; ++it) {
        int len = lens[it];                       // uniform -> scalar load
        bool v  = (i < len) && (j < len);
        f2 dd = *reinterpret_cast<const f2*>(matp + (size_t)it * (65536 * 2));
        f4 ba = v ? base1a : base0a;  f4 bb = v ? base1b : base0b;
        f4 ca = v ? cs1a   : cs0a;    f4 cb = v ? cs1b   : cs0b;
        f4 ta = v ? ct1a   : ct0a;    f4 tb = v ? ct1b   : ct0b;
        f4 o0 = ba + dd.x * ca + dd.y * ta;
        f4 o1 = bb + dd.x * cb + dd.y * tb;
        st4nt(outp + (size_t)it * DELTA_IT_STRIDE,     o0);
        st4nt(outp + (size_t)it * DELTA_IT_STRIDE + 4, o1);
    }
}

extern "C" void kernel_launch(void* const* d_in, const int* in_sizes, int n_in,
                              void* d_out, int out_size, void* d_ws, size_t ws_size,
                              hipStream_t stream) {
    const int*   traj   = (const int*)  d_in[0];
    const float* mat    = (const float*)d_in[1];
    const int*   lens   = (const int*)  d_in[2];
    const float* emb_t  = (const float*)d_in[3];
    const float* emb_l  = (const float*)d_in[4];
    const float* emb_u  = (const float*)d_in[5];
    const float* emb_su = (const float*)d_in[6];
    const float* emb_sl = (const float*)d_in[7];
    const float* emb_tu = (const float*)d_in[8];
    const float* emb_tl = (const float*)d_in[9];
    float* out = (float*)d_out;

    ctr_fused_kernel<<<2048, 256, 0, stream>>>(
        traj, mat, lens, emb_t, emb_l, emb_u, emb_su, emb_sl, emb_tu, emb_tl, out);
}

// Round 3
// 29.066 us; speedup vs baseline: 2.3098x; 2.3098x over previous
//
#include <hip/hip_runtime.h>

// CTRMultiEmbedding: joint embedding gather + bilinear interval embedding.
// out = [joint (B,L,D) | delta (B,L,L,D)] concatenated, float32.
// delta[b,i,j,d] = base[m][d] + ds*cs[m][d] + dt*ct[m][d]
//   m = (i<len_b && j<len_b); base = e_sl+e_tl, cs = e_su-e_sl, ct = e_tu-e_tl.
//
// Round-1 structure (grid-stride, 16B/thread/iter, PLAIN stores — NT stores
// regressed 2.5x in round 2). Single delta vs round 1: interpolation
// coefficients hoisted from LDS into 6 f4 registers (d4 = g&15 is
// loop-invariant since stride 2^19 % 16 == 0); mask select via cndmask.

typedef float f4 __attribute__((ext_vector_type(4)));
typedef float f2 __attribute__((ext_vector_type(2)));

constexpr int HOURS   = 168;
constexpr int Dd      = 64;
constexpr int NJOINT4 = 8 * 256 * 64 / 4;          // 32768 float4
constexpr int NPAIR   = 8 * 256 * 256;             // 524288
constexpr int NDELTA4 = NPAIR * Dd / 4;            // 8,388,608 float4
constexpr int NTOT4   = NJOINT4 + NDELTA4;

__device__ __forceinline__ f4 ld4(const float* p) {
    return *reinterpret_cast<const f4*>(p);
}

__global__ __launch_bounds__(256) void ctr_fused_kernel(
    const int*   __restrict__ traj,     // (B,L,3) int32
    const float* __restrict__ mat,      // (B,L,L,2)
    const int*   __restrict__ lens,     // (B)
    const float* __restrict__ emb_t,    // (169,64)
    const float* __restrict__ emb_l,    // (50000,64)
    const float* __restrict__ emb_u,    // (10000,64)
    const float* __restrict__ emb_su,   // (2,64)
    const float* __restrict__ emb_sl,
    const float* __restrict__ emb_tu,
    const float* __restrict__ emb_tl,
    float* __restrict__ out)
{
    __shared__ int s_len[8];

    const int tid = threadIdx.x;
    if (tid < 8) s_len[tid] = lens[tid];
    __syncthreads();

    const int tid_g = blockIdx.x * 256 + tid;
    const int dof = (tid_g & 15) * 4;   // float offset in D, loop-invariant

    // ---- hoist interpolation coefficients into registers (6 x f4) ----
    f4 sl0 = ld4(emb_sl + dof), sl1 = ld4(emb_sl + 64 + dof);
    f4 su0 = ld4(emb_su + dof), su1 = ld4(emb_su + 64 + dof);
    f4 tl0 = ld4(emb_tl + dof), tl1 = ld4(emb_tl + 64 + dof);
    f4 tu0 = ld4(emb_tu + dof), tu1 = ld4(emb_tu + 64 + dof);

    const f4 base0 = sl0 + tl0, base1 = sl1 + tl1;
    const f4 cs0   = su0 - sl0, cs1   = su1 - sl1;
    const f4 ct0   = tu0 - tl0, ct1   = tu1 - tl1;

    const int stride = gridDim.x * 256;
    for (int g = tid_g; g < NTOT4; g += stride) {
        if (g < NJOINT4) {
            // ---- joint embedding: row = b*L + l, 16 float4 per row ----
            int row = g >> 4;
            int user = traj[row * 3 + 0];
            int loc  = traj[row * 3 + 1];
            int t    = traj[row * 3 + 2];
            int tm = (t - 1) % HOURS;          // python modulo fixup
            if (tm < 0) tm += HOURS;
            int tx = tm + 1;
            f4 a = ld4(emb_t + tx * Dd + dof);
            f4 l = ld4(emb_l + loc * Dd + dof);
            f4 u = ld4(emb_u + user * Dd + dof);
            *reinterpret_cast<f4*>(&out[(size_t)g * 4]) = a + l + u;
        } else {
            // ---- delta embedding ----
            int di   = g - NJOINT4;
            int pair = di >> 4;                // b*65536 + i*256 + j
            int b  = pair >> 16;
            int i  = (pair >> 8) & 255;
            int j  = pair & 255;
            int len = s_len[b];                // wave-uniform broadcast read
            bool v = (i < len) && (j < len);
            f2 dd = *reinterpret_cast<const f2*>(&mat[(size_t)pair * 2]);
            f4 ba = v ? base1 : base0;
            f4 ca = v ? cs1   : cs0;
            f4 ta = v ? ct1   : ct0;
            f4 o = ba + dd.x * ca + dd.y * ta;
            *reinterpret_cast<f4*>(&out[(size_t)g * 4]) = o;
        }
    }
}

extern "C" void kernel_launch(void* const* d_in, const int* in_sizes, int n_in,
                              void* d_out, int out_size, void* d_ws, size_t ws_size,
                              hipStream_t stream) {
    const int*   traj   = (const int*)  d_in[0];
    const float* mat    = (const float*)d_in[1];
    const int*   lens   = (const int*)  d_in[2];
    const float* emb_t  = (const float*)d_in[3];
    const float* emb_l  = (const float*)d_in[4];
    const float* emb_u  = (const float*)d_in[5];
    const float* emb_su = (const float*)d_in[6];
    const float* emb_sl = (const float*)d_in[7];
    const float* emb_tu = (const float*)d_in[8];
    const float* emb_tl = (const float*)d_in[9];
    float* out = (float*)d_out;

    ctr_fused_kernel<<<2048, 256, 0, stream>>>(
        traj, mat, lens, emb_t, emb_l, emb_u, emb_su, emb_sl, emb_tu, emb_tl, out);
}

// Round 4
// 27.711 us; speedup vs baseline: 2.4227x; 1.0489x over previous
//
#include <hip/hip_runtime.h>

// CTRMultiEmbedding: joint embedding gather + bilinear interval embedding.
// out = [joint (B,L,D) | delta (B,L,L,D)] concatenated, float32.
// delta[b,i,j,d] = base[m][d] + ds*cs[m][d] + dt*ct[m][d]
//   m = (i<len_b && j<len_b); base = e_sl+e_tl, cs = e_su-e_sl, ct = e_tu-e_tl.
//
// Round 4: fully-unrolled-over-batch structure (8 independent mat loads in
// flight, 16 independent stores -> max per-thread MLP), PLAIN stores (NT
// stores caused round-2's 2.5x regression: they bypass L2 write-combining
// and our per-instruction store pattern was half-line). Store layout: each
// thread owns floats [d4,d4+4) and [d4+32,d4+36) of its 64-float pair-row,
// so every wave-store covers 32 full aligned 128-B lines. Coefficients
// staged LDS-once-per-block (avoids global broadcast hotspot), then live in
// 12 f4 registers.

typedef float f4 __attribute__((ext_vector_type(4)));
typedef float f2 __attribute__((ext_vector_type(2)));

constexpr int HOURS  = 168;
constexpr int Dd     = 64;
constexpr int NJOINT = 8 * 256 * 64;           // 131072 floats
constexpr int BSTRIDE = 256 * 256 * 64;        // floats per batch in delta

__device__ __forceinline__ f4 ld4(const float* p) {
    return *reinterpret_cast<const f4*>(p);
}

__global__ __launch_bounds__(256) void ctr_fused_kernel(
    const int*   __restrict__ traj,     // (B,L,3) int32
    const float* __restrict__ mat,      // (B,L,L,2)
    const int*   __restrict__ lens,     // (B)
    const float* __restrict__ emb_t,    // (169,64)
    const float* __restrict__ emb_l,    // (50000,64)
    const float* __restrict__ emb_u,    // (10000,64)
    const float* __restrict__ emb_su,   // (2,64)
    const float* __restrict__ emb_sl,
    const float* __restrict__ emb_tu,
    const float* __restrict__ emb_tl,
    float* __restrict__ out)
{
    __shared__ float s_base[2][64], s_cs[2][64], s_ct[2][64];
    __shared__ int   s_len[8];

    const int tid = threadIdx.x;
    if (tid < 128) {
        int m = tid >> 6, d = tid & 63;
        float sl = emb_sl[tid], su = emb_su[tid];
        float tl = emb_tl[tid], tu = emb_tu[tid];
        s_base[m][d] = sl + tl;
        s_cs[m][d]   = su - sl;
        s_ct[m][d]   = tu - tl;
    }
    if (tid < 8) s_len[tid] = lens[tid];
    __syncthreads();

    const int tid_g = blockIdx.x * 256 + tid;   // 0 .. 2^19-1
    const int d4 = (tid_g & 7) * 4;             // first-half float offset
    const int p0 = tid_g >> 3;                  // i*256 + j
    const int i  = p0 >> 8;
    const int j  = p0 & 255;

    // ---- coefficients -> 12 f4 registers (one-time LDS reads) ----
    const f4 b0a = ld4(&s_base[0][d4]), b0b = ld4(&s_base[0][d4 + 32]);
    const f4 b1a = ld4(&s_base[1][d4]), b1b = ld4(&s_base[1][d4 + 32]);
    const f4 c0a = ld4(&s_cs[0][d4]),   c0b = ld4(&s_cs[0][d4 + 32]);
    const f4 c1a = ld4(&s_cs[1][d4]),   c1b = ld4(&s_cs[1][d4 + 32]);
    const f4 t0a = ld4(&s_ct[0][d4]),   t0b = ld4(&s_ct[0][d4 + 32]);
    const f4 t1a = ld4(&s_ct[1][d4]),   t1b = ld4(&s_ct[1][d4 + 32]);

    // ---- joint embedding: first 16384 threads, one row-half-pair each ----
    if (tid_g < NJOINT / 8) {
        int row  = tid_g >> 3;
        int user = traj[row * 3 + 0];
        int loc  = traj[row * 3 + 1];
        int t    = traj[row * 3 + 2];
        int tm = (t - 1) % HOURS;               // python modulo fixup
        if (tm < 0) tm += HOURS;
        int tx = tm + 1;
        f4 o1 = ld4(emb_t + tx * Dd + d4)
              + ld4(emb_l + loc * Dd + d4)
              + ld4(emb_u + user * Dd + d4);
        f4 o2 = ld4(emb_t + tx * Dd + d4 + 32)
              + ld4(emb_l + loc * Dd + d4 + 32)
              + ld4(emb_u + user * Dd + d4 + 32);
        *reinterpret_cast<f4*>(&out[row * Dd + d4])      = o1;
        *reinterpret_cast<f4*>(&out[row * Dd + d4 + 32]) = o2;
    }

    // ---- delta embedding: unrolled over batch, loads first ----
    const float* matp = mat + (size_t)p0 * 2;
    float*       outp = out + NJOINT + (size_t)p0 * Dd + d4;

    f2 dd[8];
#pragma unroll
    for (int it = 0; it < 8; ++it)
        dd[it] = *reinterpret_cast<const f2*>(matp + (size_t)it * (65536 * 2));

#pragma unroll
    for (int it = 0; it < 8; ++it) {
        int len = s_len[it];
        bool v  = (i < len) && (j < len);
        f4 ba = v ? b1a : b0a;  f4 bb = v ? b1b : b0b;
        f4 ca = v ? c1a : c0a;  f4 cb = v ? c1b : c0b;
        f4 ta = v ? t1a : t0a;  f4 tb = v ? t1b : t0b;
        f4 oA = ba + dd[it].x * ca + dd[it].y * ta;
        f4 oB = bb + dd[it].x * cb + dd[it].y * tb;
        *reinterpret_cast<f4*>(outp + (size_t)it * BSTRIDE)      = oA;
        *reinterpret_cast<f4*>(outp + (size_t)it * BSTRIDE + 32) = oB;
    }
}

extern "C" void kernel_launch(void* const* d_in, const int* in_sizes, int n_in,
                              void* d_out, int out_size, void* d_ws, size_t ws_size,
                              hipStream_t stream) {
    const int*   traj   = (const int*)  d_in[0];
    const float* mat    = (const float*)d_in[1];
    const int*   lens   = (const int*)  d_in[2];
    const float* emb_t  = (const float*)d_in[3];
    const float* emb_l  = (const float*)d_in[4];
    const float* emb_u  = (const float*)d_in[5];
    const float* emb_su = (const float*)d_in[6];
    const float* emb_sl = (const float*)d_in[7];
    const float* emb_tu = (const float*)d_in[8];
    const float* emb_tl = (const float*)d_in[9];
    float* out = (float*)d_out;

    ctr_fused_kernel<<<2048, 256, 0, stream>>>(
        traj, mat, lens, emb_t, emb_l, emb_u, emb_su, emb_sl, emb_tu, emb_tl, out);
}